// Round 5
// baseline (12914.380 us; speedup 1.0000x reference)
//
#include <hip/hip_runtime.h>

#define B_   256
#define T_   512
#define H_   512
#define C_   10
#define NGRP 8      // batch groups (32 batches each)
#define BPG  32
#define JT   16     // j-outputs per block
#define NJT  32     // blocks per batch group
#define NTHR 512    // 8 waves x 4 batches/wave; 2 waves/SIMD TLP
#define WF   (4 * JT * H_)   // 32768 floats: W'[kc=128][gj=64][kk=4] = 128 KiB
#define HCH  2048            // floats per h buffer: [32 b][64 k] = 8 KiB
// 128K (W) + 2x8K (h dbuf) = 144 KiB -> 1 block/CU
#define LDS_BYTES ((WF + 2 * HCH) * 4)

// numpy-SIMD-style (cephes/avx_mathfun) f32 exp — r9-flagged V2 model. DO NOT TOUCH.
__device__ __forceinline__ float expf_cephes(float x) {
    x = fminf(x, 88.3762626647949f);
    x = fmaxf(x, -88.3762626647949f);
    float fx = __fmaf_rn(x, 1.44269504088896341f, 0.5f);
    fx = floorf(fx);
    x = __fmaf_rn(fx, -0.693359375f, x);
    x = __fmaf_rn(fx, 2.12194440e-4f, x);
    float z = __fmul_rn(x, x);
    float y = 1.9875691500E-4f;
    y = __fmaf_rn(y, x, 1.3981999507E-3f);
    y = __fmaf_rn(y, x, 8.3334519073E-3f);
    y = __fmaf_rn(y, x, 4.1665795894E-2f);
    y = __fmaf_rn(y, x, 1.6666665459E-1f);
    y = __fmaf_rn(y, x, 5.0000001201E-1f);
    y = __fmaf_rn(y, z, x);
    y = __fadd_rn(y, 1.0f);
    return ldexpf(y, (int)fx);
}

__device__ __forceinline__ float sig_np(float pre) {
    float e = expf_cephes(-pre);
    return __fdiv_rn(1.0f, __fadd_rn(1.0f, e));
}

// Zero-VGPR async global->LDS stage (16 B/lane) — r4-proven.
__device__ __forceinline__ void stage_h16(const float* g, float* l) {
    __builtin_amdgcn_global_load_lds(
        (const __attribute__((address_space(1))) void*)g,
        (__attribute__((address_space(3))) void*)l, 16, 0, 0);
}

// v_readlane_b32: VALU-pipe broadcast of a wave-uniform h scalar into an SGPR.
// Pure data movement (bit-exact); lane index is a compile-time constant after
// unroll. Replaces uniform-address ds_read_b128 broadcasts, which r4's counters
// proved cost full LDS return bandwidth (1024 B crossbar for 16 B of data).
__device__ __forceinline__ float rdl(float v, int lane) {
    return __int_as_float(__builtin_amdgcn_readlane(__float_as_int(v), lane));
}

// Epilogue per batch: gather all 4 gate pre-activations to every lane via
// ds_bpermute (pure data movement — values are the bit-exact per-gate chains),
// then V2 rounding verbatim. All 4 gate-groups compute c/h redundantly
// (identical deterministic ops); gate-group g stores batch bi==g.
#define EPI(bi, av, cv)                                                         \
    {                                                                           \
        const float pre = __fadd_rn(__fadd_rn(__fmul_rn(wx, xt##bi), av), bs);  \
        const int pbits = __float_as_int(pre);                                  \
        const float pg = __int_as_float(__builtin_amdgcn_ds_bpermute(ix0, pbits)); \
        const float pi = __int_as_float(__builtin_amdgcn_ds_bpermute(ix1, pbits)); \
        const float pf = __int_as_float(__builtin_amdgcn_ds_bpermute(ix2, pbits)); \
        const float po = __int_as_float(__builtin_amdgcn_ds_bpermute(ix3, pbits)); \
        const float iv = sig_np(pi);                                            \
        const float fv = sig_np(pf);                                            \
        const float ov = sig_np(po);                                            \
        cv = __fadd_rn(__fmul_rn(pg, iv), __fmul_rn(cv, fv));                   \
        const float hn = __fmul_rn(cv, ov);                                     \
        if ((bi) == g) hwp[(bi) * H_] = hn;                                     \
    }

__global__ void __launch_bounds__(NTHR, 1) lstm_fast(
    const float* __restrict__ x,
    const float* __restrict__ wgh, const float* __restrict__ wih,
    const float* __restrict__ wfh, const float* __restrict__ woh,
    const float* __restrict__ wgx, const float* __restrict__ wix,
    const float* __restrict__ wfx, const float* __restrict__ wox,
    const float* __restrict__ bgp, const float* __restrict__ bip,
    const float* __restrict__ bfp, const float* __restrict__ bop,
    float* __restrict__ hbuf, unsigned int* __restrict__ cnt)
{
    extern __shared__ float lds[];   // [W' 128K][h buf0 8K][h buf1 8K]
    const int tid = threadIdx.x;
    const int bg  = blockIdx.x & (NGRP - 1);
    const int jt  = blockIdx.x >> 3;
    const int j0  = jt * JT;

    // stage W': lds[(k>>2)*256 + (g*16+jj)*4 + (k&3)] = W_g[k][j0+jj]  (exact bits)
    const float* wh[4] = {wgh, wih, wfh, woh};
    for (int g2 = 0; g2 < 4; ++g2) {
        const float* w = wh[g2];
        for (int idx = tid; idx < H_ * JT; idx += NTHR) {
            const int k   = idx >> 4;
            const int jj2 = idx & (JT - 1);
            lds[((k >> 2) << 8) + (((g2 << 4) + jj2) << 2) + (k & 3)] =
                w[k * H_ + j0 + jj2];
        }
    }
    __syncthreads();

    // lane mapping: l = (gate g, column jj); wave wv owns 4 batches.
    const int l   = tid & 63;
    const int wv  = tid >> 6;                 // 0..7
    const int g   = l >> 4;
    const int jj  = l & 15;
    const int jg  = j0 + jj;
    const int b0w = bg * BPG + wv * 4;

    const float* wxs = (g == 0) ? wgx : (g == 1) ? wix : (g == 2) ? wfx : wox;
    const float* bss = (g == 0) ? bgp : (g == 1) ? bip : (g == 2) ? bfp : bop;
    const float wx = wxs[jg];
    const float bs = bss[jg];

    // bpermute byte-indices: gate-0..3 lanes holding this jj
    const int ix0 = (jj + 0)  << 2;
    const int ix1 = (jj + 16) << 2;
    const int ix2 = (jj + 32) << 2;
    const int ix3 = (jj + 48) << 2;

    const float4* wr = (const float4*)lds;
    float* hls = lds + WF;                    // h staging region
    // stage geometry: wave wv covers its 4 batches x 64 k = 1024 B at base wv KiB;
    // lane l writes base + l*16 -> hls[buf][4*wv + (l>>4)][64k] LINEAR.
    float* stage_base = hls + wv * 256;       // + bsel*HCH at use
    const int bsrc = (b0w + (l >> 4)) * H_ + ((l & 15) << 2);   // float offset in hb

    float c0 = 0.f, c1 = 0.f, c2 = 0.f, c3 = 0.f;

    for (int t = 0; t < T_; ++t) {
        if (t > 0) {
            if (tid == 0) {
                while (__hip_atomic_load(&cnt[t * NGRP + bg], __ATOMIC_RELAXED,
                                         __HIP_MEMORY_SCOPE_AGENT) < NJT) {
                    __builtin_amdgcn_s_sleep(1);
                }
                (void)__hip_atomic_load(&cnt[t * NGRP + bg], __ATOMIC_ACQUIRE,
                                        __HIP_MEMORY_SCOPE_AGENT);
            }
            __syncthreads();
        }

        const float xt0 = x[(b0w + 0) * T_ + t];
        const float xt1 = x[(b0w + 1) * T_ + t];
        const float xt2 = x[(b0w + 2) * T_ + t];
        const float xt3 = x[(b0w + 3) * T_ + t];

        const float* hb = hbuf + (size_t)(t & 1) * B_ * H_;

        float a0 = 0.f, a1 = 0.f, a2 = 0.f, a3 = 0.f;

        // prologue: stage super-chunk 0 (k 0..63) into h buf 0
        stage_h16(hb + bsrc, stage_base);
        __syncthreads();   // drains vmcnt -> buf0 ready

        // 8 super-chunks of 64 k; LDS-light inner loop, DMA prefetch 1 ahead.
        #pragma unroll 1
        for (int sc = 0; sc < 8; ++sc) {
            const int bsel = sc & 1;
            if (sc < 7) {
                stage_h16(hb + bsrc + ((sc + 1) << 6), stage_base + (bsel ^ 1) * HCH);
                __builtin_amdgcn_sched_barrier(0);   // pin issue point (no reg cost)
            }
            // ONE lane-distinct b128: lane l -> h[batch l>>4][kquad l&15] (4 VGPR).
            // All h broadcasts below are readlanes (VALU) — zero LDS-pipe cost.
            const float4 hreg = ((const float4*)(hls + bsel * HCH))[(wv << 6) + l];
            const int kc0 = sc << 4;
            #pragma unroll
            for (int c = 0; c < 16; ++c) {
                const float4 w4 = wr[((kc0 + c) << 6) + l];
                float s;
                // batch 0 chain, k = 4c..4c+3 ascending (bit-identical order)
                s = rdl(hreg.x, c);      a0 = __fmaf_rn(s, w4.x, a0);
                s = rdl(hreg.y, c);      a0 = __fmaf_rn(s, w4.y, a0);
                s = rdl(hreg.z, c);      a0 = __fmaf_rn(s, w4.z, a0);
                s = rdl(hreg.w, c);      a0 = __fmaf_rn(s, w4.w, a0);
                // batch 1
                s = rdl(hreg.x, 16 + c); a1 = __fmaf_rn(s, w4.x, a1);
                s = rdl(hreg.y, 16 + c); a1 = __fmaf_rn(s, w4.y, a1);
                s = rdl(hreg.z, 16 + c); a1 = __fmaf_rn(s, w4.z, a1);
                s = rdl(hreg.w, 16 + c); a1 = __fmaf_rn(s, w4.w, a1);
                // batch 2
                s = rdl(hreg.x, 32 + c); a2 = __fmaf_rn(s, w4.x, a2);
                s = rdl(hreg.y, 32 + c); a2 = __fmaf_rn(s, w4.y, a2);
                s = rdl(hreg.z, 32 + c); a2 = __fmaf_rn(s, w4.z, a2);
                s = rdl(hreg.w, 32 + c); a2 = __fmaf_rn(s, w4.w, a2);
                // batch 3
                s = rdl(hreg.x, 48 + c); a3 = __fmaf_rn(s, w4.x, a3);
                s = rdl(hreg.y, 48 + c); a3 = __fmaf_rn(s, w4.y, a3);
                s = rdl(hreg.z, 48 + c); a3 = __fmaf_rn(s, w4.z, a3);
                s = rdl(hreg.w, 48 + c); a3 = __fmaf_rn(s, w4.w, a3);
            }
            // barrier: (a) next stage vmcnt-drained, (b) all waves done with bsel
            __syncthreads();
        }

        float* hw  = hbuf + (size_t)((t + 1) & 1) * B_ * H_;
        float* hwp = hw + b0w * H_ + jg;

        EPI(0, a0, c0) EPI(1, a1, c1) EPI(2, a2, c2) EPI(3, a3, c3)

        __syncthreads();   // s_waitcnt vmcnt(0) before s_barrier: h stores drained
        if (tid == 0) {
            // RELEASE fetch_add alone provides the store->flag release fence.
            __hip_atomic_fetch_add(&cnt[(t + 1) * NGRP + bg], 1u,
                                   __ATOMIC_RELEASE, __HIP_MEMORY_SCOPE_AGENT);
        }
    }
}

// out[b][c] = dot_seq(h_T[b], wph[c]) + bp[c]  — bit-identical chain to r12's proj
__global__ void __launch_bounds__(64) proj_kernel(
    const float* __restrict__ hbuf, const float* __restrict__ wph,
    const float* __restrict__ bp, float* __restrict__ out)
{
    const int b = blockIdx.x, tid = threadIdx.x;
    const float* h = hbuf + (size_t)b * H_;   // final h in buffer 0 (T even)
    if (tid < C_) {
        float acc = 0.f;
        for (int k = 0; k < H_; ++k)
            acc = __fmaf_rn(h[k], wph[tid * H_ + k], acc);
        out[b * C_ + tid] = __fadd_rn(acc, bp[tid]);
    }
}

extern "C" void kernel_launch(void* const* d_in, const int* in_sizes, int n_in,
                              void* d_out, int out_size, void* d_ws, size_t ws_size,
                              hipStream_t stream)
{
    const float* x   = (const float*)d_in[0];
    const float* wgx = (const float*)d_in[1];
    const float* wgh = (const float*)d_in[2];
    const float* bgp = (const float*)d_in[3];
    const float* wix = (const float*)d_in[4];
    const float* wih = (const float*)d_in[5];
    const float* bip = (const float*)d_in[6];
    const float* wfx = (const float*)d_in[7];
    const float* wfh = (const float*)d_in[8];
    const float* bfp = (const float*)d_in[9];
    const float* wox = (const float*)d_in[10];
    const float* woh = (const float*)d_in[11];
    const float* bop = (const float*)d_in[12];
    const float* wph = (const float*)d_in[13];
    const float* bp  = (const float*)d_in[14];
    float* out = (float*)d_out;

    float* hbuf = (float*)d_ws;                                   // 2*B*H f32 = 1 MB
    unsigned int* cnt = (unsigned int*)((char*)d_ws + (size_t)2 * B_ * H_ * 4);
    size_t zero_bytes = (size_t)2 * B_ * H_ * 4 + (size_t)(T_ + 1) * NGRP * 4;
    hipMemsetAsync(d_ws, 0, zero_bytes, stream);   // h0 = 0, counters = 0

    hipFuncSetAttribute((const void*)lstm_fast,
                        hipFuncAttributeMaxDynamicSharedMemorySize, LDS_BYTES);

    void* args[] = {&x, &wgh, &wih, &wfh, &woh, &wgx, &wix, &wfx, &wox,
                    &bgp, &bip, &bfp, &bop, &hbuf, &cnt};
    hipLaunchCooperativeKernel((const void*)lstm_fast, dim3(NGRP * NJT), dim3(NTHR),
                               args, LDS_BYTES, stream);

    proj_kernel<<<B_, 64, 0, stream>>>(hbuf, wph, bp, out);
}

// Round 6
// 12206.336 us; speedup vs baseline: 1.0580x; 1.0580x over previous
//
#include <hip/hip_runtime.h>

#define B_   256
#define T_   512
#define H_   512
#define C_   10
#define NGRP 8      // batch groups (32 batches each)
#define BPG  32
#define JT   16     // j-outputs per block
#define NJT  32     // blocks per batch group
#define NTHR 512    // 8 waves x 4 batches/wave; 2 waves/SIMD TLP
#define WF   (4 * JT * H_)   // 32768 floats: W'[kc=128][gj=64][kk=4] = 128 KiB
#define HCH  2048            // floats per h buffer: [8 waves][4 b][64 k] = 8 KiB
// 128K (W) + 2x8K (h dbuf) = 144 KiB -> 1 block/CU
#define LDS_BYTES ((WF + 2 * HCH) * 4)

// numpy-SIMD-style (cephes/avx_mathfun) f32 exp — r9-flagged V2 model. DO NOT TOUCH.
__device__ __forceinline__ float expf_cephes(float x) {
    x = fminf(x, 88.3762626647949f);
    x = fmaxf(x, -88.3762626647949f);
    float fx = __fmaf_rn(x, 1.44269504088896341f, 0.5f);
    fx = floorf(fx);
    x = __fmaf_rn(fx, -0.693359375f, x);
    x = __fmaf_rn(fx, 2.12194440e-4f, x);
    float z = __fmul_rn(x, x);
    float y = 1.9875691500E-4f;
    y = __fmaf_rn(y, x, 1.3981999507E-3f);
    y = __fmaf_rn(y, x, 8.3334519073E-3f);
    y = __fmaf_rn(y, x, 4.1665795894E-2f);
    y = __fmaf_rn(y, x, 1.6666665459E-1f);
    y = __fmaf_rn(y, x, 5.0000001201E-1f);
    y = __fmaf_rn(y, z, x);
    y = __fadd_rn(y, 1.0f);
    return ldexpf(y, (int)fx);
}

__device__ __forceinline__ float sig_np(float pre) {
    float e = expf_cephes(-pre);
    return __fdiv_rn(1.0f, __fadd_rn(1.0f, e));
}

// Zero-VGPR async global->LDS stage (16 B/lane) — r4-proven.
__device__ __forceinline__ void stage_h16(const float* g, float* l) {
    __builtin_amdgcn_global_load_lds(
        (const __attribute__((address_space(1))) void*)g,
        (__attribute__((address_space(3))) void*)l, 16, 0, 0);
}

// v_readlane_b32 broadcast (bit-exact data movement). r5 counters showed the
// compiler pairing each readlane with its consuming FMA -> SGPR-write->VALU-read
// wait states inflated VALU ~2x. r6 groups 16 readlanes then 16 FMAs so every
// FMA is >=12 instructions after its producer.
__device__ __forceinline__ float rdl(float v, int lane) {
    return __int_as_float(__builtin_amdgcn_readlane(__float_as_int(v), lane));
}

// Epilogue per batch: gather all 4 gate pre-activations to every lane via
// ds_bpermute (pure data movement — values are the bit-exact per-gate chains),
// then V2 rounding verbatim. All 4 gate-groups compute c/h redundantly
// (identical deterministic ops); gate-group g stores batch bi==g.
#define EPI(bi, av, cv)                                                         \
    {                                                                           \
        const float pre = __fadd_rn(__fadd_rn(__fmul_rn(wx, xt##bi), av), bs);  \
        const int pbits = __float_as_int(pre);                                  \
        const float pg = __int_as_float(__builtin_amdgcn_ds_bpermute(ix0, pbits)); \
        const float pi = __int_as_float(__builtin_amdgcn_ds_bpermute(ix1, pbits)); \
        const float pf = __int_as_float(__builtin_amdgcn_ds_bpermute(ix2, pbits)); \
        const float po = __int_as_float(__builtin_amdgcn_ds_bpermute(ix3, pbits)); \
        const float iv = sig_np(pi);                                            \
        const float fv = sig_np(pf);                                            \
        const float ov = sig_np(po);                                            \
        cv = __fadd_rn(__fmul_rn(pg, iv), __fmul_rn(cv, fv));                   \
        const float hn = __fmul_rn(cv, ov);                                     \
        if ((bi) == g) hwp[(bi) * H_] = hn;                                     \
    }

__global__ void __launch_bounds__(NTHR, 1) lstm_fast(
    const float* __restrict__ x,
    const float* __restrict__ wgh, const float* __restrict__ wih,
    const float* __restrict__ wfh, const float* __restrict__ woh,
    const float* __restrict__ wgx, const float* __restrict__ wix,
    const float* __restrict__ wfx, const float* __restrict__ wox,
    const float* __restrict__ bgp, const float* __restrict__ bip,
    const float* __restrict__ bfp, const float* __restrict__ bop,
    float* __restrict__ hbuf, unsigned int* __restrict__ cnt)
{
    extern __shared__ float lds[];   // [W' 128K][h buf0 8K][h buf1 8K]
    const int tid = threadIdx.x;
    const int bg  = blockIdx.x & (NGRP - 1);
    const int jt  = blockIdx.x >> 3;
    const int j0  = jt * JT;

    // stage W': lds[(k>>2)*256 + (g*16+jj)*4 + (k&3)] = W_g[k][j0+jj]  (exact bits)
    const float* wh[4] = {wgh, wih, wfh, woh};
    for (int g2 = 0; g2 < 4; ++g2) {
        const float* w = wh[g2];
        for (int idx = tid; idx < H_ * JT; idx += NTHR) {
            const int k   = idx >> 4;
            const int jj2 = idx & (JT - 1);
            lds[((k >> 2) << 8) + (((g2 << 4) + jj2) << 2) + (k & 3)] =
                w[k * H_ + j0 + jj2];
        }
    }
    __syncthreads();

    // lane mapping: l = (gate g, column jj); wave wv owns 4 batches.
    const int l   = tid & 63;
    const int wv  = tid >> 6;                 // 0..7
    const int g   = l >> 4;
    const int jj  = l & 15;
    const int jg  = j0 + jj;
    const int b0w = bg * BPG + wv * 4;

    const float* wxs = (g == 0) ? wgx : (g == 1) ? wix : (g == 2) ? wfx : wox;
    const float* bss = (g == 0) ? bgp : (g == 1) ? bip : (g == 2) ? bfp : bop;
    const float wx = wxs[jg];
    const float bs = bss[jg];

    // bpermute byte-indices: gate-0..3 lanes holding this jj
    const int ix0 = (jj + 0)  << 2;
    const int ix1 = (jj + 16) << 2;
    const int ix2 = (jj + 32) << 2;
    const int ix3 = (jj + 48) << 2;

    const float4* wr = (const float4*)lds;
    float* hls = lds + WF;                    // h staging region
    // WAVE-PRIVATE staging: wave wv DMAs its 4 batches x 64 k (1 KiB) into
    // hls[buf] + wv KiB and ONLY wave wv reads it. No cross-wave sharing ->
    // per-sc __syncthreads (8/step in r4/r5) replaced by per-wave vmcnt(0).
    float* stage_base = hls + wv * 256;       // + bsel*HCH at use
    const int bsrc = (b0w + (l >> 4)) * H_ + ((l & 15) << 2);   // float offset in hb

    float c0 = 0.f, c1 = 0.f, c2 = 0.f, c3 = 0.f;

    for (int t = 0; t < T_; ++t) {
        if (t > 0) {
            if (tid == 0) {
                while (__hip_atomic_load(&cnt[t * NGRP + bg], __ATOMIC_RELAXED,
                                         __HIP_MEMORY_SCOPE_AGENT) < NJT) {
                    __builtin_amdgcn_s_sleep(1);
                }
                (void)__hip_atomic_load(&cnt[t * NGRP + bg], __ATOMIC_ACQUIRE,
                                        __HIP_MEMORY_SCOPE_AGENT);
            }
            __syncthreads();   // protocol barrier 1: h[t] visible to all waves
        }

        const float xt0 = x[(b0w + 0) * T_ + t];
        const float xt1 = x[(b0w + 1) * T_ + t];
        const float xt2 = x[(b0w + 2) * T_ + t];
        const float xt3 = x[(b0w + 3) * T_ + t];

        const float* hb = hbuf + (size_t)(t & 1) * B_ * H_;

        float a0 = 0.f, a1 = 0.f, a2 = 0.f, a3 = 0.f;

        // prologue: stage super-chunk 0 (k 0..63) into h buf 0
        stage_h16(hb + bsrc, stage_base);

        // 8 super-chunks of 64 k; FREE-RUNNING per wave (no block barriers).
        #pragma unroll 1
        for (int sc = 0; sc < 8; ++sc) {
            const int bsel = sc & 1;
            // wait for current buffer's DMA (per-wave; also drains prior stores).
            // "memory" clobber + sched_barrier: hreg ds_read cannot hoist above.
            asm volatile("s_waitcnt vmcnt(0)" ::: "memory");
            __builtin_amdgcn_sched_barrier(0);
            if (sc < 7) {
                // prefetch next super-chunk into other buffer. That buffer was
                // last READ in sc-1 (program order, same wave) -> safe.
                stage_h16(hb + bsrc + ((sc + 1) << 6), stage_base + (bsel ^ 1) * HCH);
            }
            // ONE lane-distinct b128: lane l -> h[batch l>>4][kquad l&15].
            const float4 hreg = ((const float4*)(hls + bsel * HCH))[(wv << 6) + l];
            const int kc0 = sc << 4;
            #pragma unroll
            for (int c = 0; c < 16; ++c) {
                const float4 w4 = wr[((kc0 + c) << 6) + l];
                // group 1: all 16 readlanes (SGPR producers)
                const float s00 = rdl(hreg.x, c);
                const float s01 = rdl(hreg.y, c);
                const float s02 = rdl(hreg.z, c);
                const float s03 = rdl(hreg.w, c);
                const float s10 = rdl(hreg.x, 16 + c);
                const float s11 = rdl(hreg.y, 16 + c);
                const float s12 = rdl(hreg.z, 16 + c);
                const float s13 = rdl(hreg.w, 16 + c);
                const float s20 = rdl(hreg.x, 32 + c);
                const float s21 = rdl(hreg.y, 32 + c);
                const float s22 = rdl(hreg.z, 32 + c);
                const float s23 = rdl(hreg.w, 32 + c);
                const float s30 = rdl(hreg.x, 48 + c);
                const float s31 = rdl(hreg.y, 48 + c);
                const float s32 = rdl(hreg.z, 48 + c);
                const float s33 = rdl(hreg.w, 48 + c);
                // group 2: 16 FMAs, each >=12 instrs after its producer.
                // Per-accumulator k order unchanged (4c,4c+1,4c+2,4c+3) ->
                // chains bit-identical to r5 (interleaving across independent
                // accumulators does not alter any chain's value).
                a0 = __fmaf_rn(s00, w4.x, a0);
                a1 = __fmaf_rn(s10, w4.x, a1);
                a2 = __fmaf_rn(s20, w4.x, a2);
                a3 = __fmaf_rn(s30, w4.x, a3);
                a0 = __fmaf_rn(s01, w4.y, a0);
                a1 = __fmaf_rn(s11, w4.y, a1);
                a2 = __fmaf_rn(s21, w4.y, a2);
                a3 = __fmaf_rn(s31, w4.y, a3);
                a0 = __fmaf_rn(s02, w4.z, a0);
                a1 = __fmaf_rn(s12, w4.z, a1);
                a2 = __fmaf_rn(s22, w4.z, a2);
                a3 = __fmaf_rn(s32, w4.z, a3);
                a0 = __fmaf_rn(s03, w4.w, a0);
                a1 = __fmaf_rn(s13, w4.w, a1);
                a2 = __fmaf_rn(s23, w4.w, a2);
                a3 = __fmaf_rn(s33, w4.w, a3);
            }
        }

        float* hw  = hbuf + (size_t)((t + 1) & 1) * B_ * H_;
        float* hwp = hw + b0w * H_ + jg;

        EPI(0, a0, c0) EPI(1, a1, c1) EPI(2, a2, c2) EPI(3, a3, c3)

        __syncthreads();   // protocol barrier 2: all h stores drained (vmcnt(0))
        if (tid == 0) {
            // RELEASE fetch_add alone provides the store->flag release fence.
            __hip_atomic_fetch_add(&cnt[(t + 1) * NGRP + bg], 1u,
                                   __ATOMIC_RELEASE, __HIP_MEMORY_SCOPE_AGENT);
        }
    }
}

// out[b][c] = dot_seq(h_T[b], wph[c]) + bp[c]  — bit-identical chain to r12's proj
__global__ void __launch_bounds__(64) proj_kernel(
    const float* __restrict__ hbuf, const float* __restrict__ wph,
    const float* __restrict__ bp, float* __restrict__ out)
{
    const int b = blockIdx.x, tid = threadIdx.x;
    const float* h = hbuf + (size_t)b * H_;   // final h in buffer 0 (T even)
    if (tid < C_) {
        float acc = 0.f;
        for (int k = 0; k < H_; ++k)
            acc = __fmaf_rn(h[k], wph[tid * H_ + k], acc);
        out[b * C_ + tid] = __fadd_rn(acc, bp[tid]);
    }
}

extern "C" void kernel_launch(void* const* d_in, const int* in_sizes, int n_in,
                              void* d_out, int out_size, void* d_ws, size_t ws_size,
                              hipStream_t stream)
{
    const float* x   = (const float*)d_in[0];
    const float* wgx = (const float*)d_in[1];
    const float* wgh = (const float*)d_in[2];
    const float* bgp = (const float*)d_in[3];
    const float* wix = (const float*)d_in[4];
    const float* wih = (const float*)d_in[5];
    const float* bip = (const float*)d_in[6];
    const float* wfx = (const float*)d_in[7];
    const float* wfh = (const float*)d_in[8];
    const float* bfp = (const float*)d_in[9];
    const float* wox = (const float*)d_in[10];
    const float* woh = (const float*)d_in[11];
    const float* bop = (const float*)d_in[12];
    const float* wph = (const float*)d_in[13];
    const float* bp  = (const float*)d_in[14];
    float* out = (float*)d_out;

    float* hbuf = (float*)d_ws;                                   // 2*B*H f32 = 1 MB
    unsigned int* cnt = (unsigned int*)((char*)d_ws + (size_t)2 * B_ * H_ * 4);
    size_t zero_bytes = (size_t)2 * B_ * H_ * 4 + (size_t)(T_ + 1) * NGRP * 4;
    hipMemsetAsync(d_ws, 0, zero_bytes, stream);   // h0 = 0, counters = 0

    hipFuncSetAttribute((const void*)lstm_fast,
                        hipFuncAttributeMaxDynamicSharedMemorySize, LDS_BYTES);

    void* args[] = {&x, &wgh, &wih, &wfh, &woh, &wgx, &wix, &wfx, &wox,
                    &bgp, &bip, &bfp, &bop, &hbuf, &cnt};
    hipLaunchCooperativeKernel((const void*)lstm_fast, dim3(NGRP * NJT), dim3(NTHR),
                               args, LDS_BYTES, stream);

    proj_kernel<<<B_, 64, 0, stream>>>(hbuf, wph, bp, out);
}